// Round 8
// baseline (230.105 us; speedup 1.0000x reference)
//
#include <hip/hip_runtime.h>
#include <stdint.h>

// Hopf oscillator scan.
// X_r, X_i: [bs=8, T=64, d=32, d=32, nk=32] fp32; omegas: [32,32,32].
// Outputs: (r*cos(phi), r*sin(phi)) each [8,64,32,32,32], concatenated.
// 262,144 independent chains over (bs,d,d,nk); T sequential.
//
// R11: producer/consumer wave specialization. R4-R10 exhausted width,
// cache policy (best: NT ld + cached st, R10 ~70us) and MLP (R9's exact
// hand vmcnt pipeline == compiler, so latency*concurrency exonerated);
// delivered BW pinned at 3.8 TB/s = 61% of the 6.29 TB/s mixed ceiling.
// Remaining structural delta vs 6+ TB/s streamers (fills, RMSNorm m238):
// they have waves that ONLY issue memory. Here: per block of 8 waves,
// waves 0-3 stream Xr/Xi into a 32KiB 8-slot LDS ring via global_load_lds
// dwordx4 (1KiB/wave-instr, nt), waves 4-7 consume via ds_read_b64
// (2-way bank alias = free), compute, cached dwordx2 stores.
// Raw s_barrier + hand-counted vmcnt (NEVER __syncthreads -- its
// vmcnt(0) drain would kill the ring), sched_barrier(0) fences (rule #18).
// 2 t-steps per window -> 33 barriers. Ring verified by induction:
// window w consumes t=2w,2w+1; issues t=2w+6,2w+7 (tenants read in w-1);
// steady vmcnt(4) retires exactly t=2w+2,2w+3 for window w+1.
// Grid 512x512 = 16 waves/CU (2 blocks/CU), LDS 32KB/block.

#define T_STEPS 64
#define CHV2    16384         // v2f chains per batch image
#define BS      8
#define CPB     256           // v2f chains per block
#define SLOTB   4096          // bytes per LDS slot: 2KB xr + 2KB xi

typedef float v2f __attribute__((ext_vector_type(2)));
typedef __attribute__((address_space(3))) uint32_t as3_u32;
typedef __attribute__((address_space(1))) uint32_t as1_u32;

__device__ __forceinline__ void gll16(const v2f* g, uint32_t lds_byte) {
    // dwordx4 direct-to-LDS, nt (CPol bit1): dest = lds_byte + lane*16
    __builtin_amdgcn_global_load_lds((const as1_u32*)g,
                                     (as3_u32*)(uintptr_t)lds_byte,
                                     16, 0, 2);
}

__global__ __launch_bounds__(512, 4)
void hopf_scan_kernel(const float* __restrict__ Xr,
                      const float* __restrict__ Xi,
                      const float* __restrict__ Om,
                      float* __restrict__ out)
{
    __shared__ __align__(16) float lds[8 * SLOTB / 4];   // 32 KiB, 8 slots

    const float DTS = 0.01f, SC = 20.0f;
    const float S1 = -1.6666667e-1f, S2 = 8.3333333e-3f,
                S3 = -1.9841270e-4f, S4 = 2.7557319e-6f;
    const float C1 = -0.5f, C2 = 4.1666667e-2f,
                C3 = -1.3888889e-3f, C4 = 2.4801587e-5f;

    const int wid  = threadIdx.x >> 6;
    const int lane = threadIdx.x & 63;
    const int blk  = blockIdx.x;
    const int b    = blk >> 6;                 // 64 blocks per batch image
    const int cv0  = (blk & 63) * CPB;
    const size_t TS = CHV2;                    // v2f elements per t-plane
    const size_t planebase = (size_t)(b * T_STEPS) * TS + cv0;

    const uint32_t ldsbase =
        (uint32_t)(uintptr_t)(__attribute__((address_space(3))) float*)lds;

    if (wid < 4) {
        // ---------------- producers: pure load stream ----------------
        // waves 0,1 -> xr halves; waves 2,3 -> xi halves. Each wave: 1KB/gll.
        const v2f* src = (wid < 2) ? (const v2f*)Xr : (const v2f*)Xi;
        const v2f* gp  = src + planebase + 2 * ((wid & 1) * 64 + lane);
        const uint32_t lboff = ldsbase + (uint32_t)((wid >> 1) * 2048 + (wid & 1) * 1024);

        // prologue: t = 0..5 into slots 0..5 (6 glls in flight)
        #pragma unroll
        for (int t = 0; t < 6; ++t)
            gll16(gp + (size_t)t * TS, lboff + (uint32_t)t * SLOTB);
        asm volatile("s_waitcnt vmcnt(4)");    // t=0,1 landed
        __builtin_amdgcn_s_barrier();
        __builtin_amdgcn_sched_barrier(0);

        const v2f* gq = gp + (size_t)6 * TS;   // next to issue: t=6
        for (int w = 0; w < 32; ++w) {
            if (w <= 28) {                      // issue t=2w+6, 2w+7
                uint32_t so = lboff + (uint32_t)(((w + 3) & 3) * 2) * SLOTB;
                gll16(gq,      so);
                gll16(gq + TS, so + SLOTB);
                gq += 2 * TS;
            }
            if (w <= 28) {
                asm volatile("s_waitcnt vmcnt(4)");   // t=2w+2,2w+3 landed
            } else if (w < 31) {
                asm volatile("s_waitcnt vmcnt(0)");   // tail drain
            }
            __builtin_amdgcn_s_barrier();
            __builtin_amdgcn_sched_barrier(0);
        }
    } else {
        // ---------------- consumers: compute + store ----------------
        const int ctid = threadIdx.x - 256;    // 0..255: one v2f chain each
        v2f omv = ((const v2f*)Om)[cv0 + ctid];
        float om[2] = {omv[0], omv[1]};
        v2f* po0 = (v2f*)out + planebase + ctid;
        v2f* po1 = po0 + (size_t)BS * T_STEPS * TS;
        float r[2]  = {1.f, 1.f};
        float co[2] = {1.f, 1.f};
        float si[2] = {0.f, 0.f};              // phi0 = 0
        const uint32_t rbase = ldsbase + (uint32_t)ctid * 8;

        __builtin_amdgcn_s_barrier();
        __builtin_amdgcn_sched_barrier(0);

        auto stepf = [&](v2f axr, v2f axi, v2f& o0, v2f& o1) {
            #pragma unroll
            for (int j = 0; j < 2; ++j) {
                float ir   = SC * axr[j] * co[j];                 // old cos
                float dphi = (om[j] - SC * axi[j] * si[j]) * DTS; // old sin
                r[j] = r[j] + ((1.f - r[j] * r[j]) * r[j] + ir) * DTS;
                float u  = dphi * dphi;
                float sp = fmaf(u, S4, S3);
                sp = fmaf(u, sp, S2);
                sp = fmaf(u, sp, S1);
                sp = fmaf(u, sp, 1.f);
                sp *= dphi;                                       // sin(dphi)
                float cp = fmaf(u, C4, C3);
                cp = fmaf(u, cp, C2);
                cp = fmaf(u, cp, C1);
                cp = fmaf(u, cp, 1.f);                            // cos(dphi)
                float nco = fmaf(co[j], cp, -si[j] * sp);
                float nsi = fmaf(si[j], cp,  co[j] * sp);
                co[j] = nco; si[j] = nsi;
                o0[j] = r[j] * co[j];
                o1[j] = r[j] * si[j];
            }
        };

        for (int w = 0; w < 32; ++w) {
            uint32_t ra0 = rbase + (uint32_t)((w & 3) * 2) * SLOTB; // slot 2w&7
            uint32_t ra1 = ra0 + SLOTB;                             // slot 2w+1
            v2f axr0, axi0, axr1, axi1;
            asm volatile("ds_read_b64 %0, %4\n\t"
                         "ds_read_b64 %1, %4 offset:2048\n\t"
                         "ds_read_b64 %2, %5\n\t"
                         "ds_read_b64 %3, %5 offset:2048\n\t"
                         "s_waitcnt lgkmcnt(0)"
                         : "=&v"(axr0), "=&v"(axi0), "=&v"(axr1), "=&v"(axi1)
                         : "v"(ra0), "v"(ra1));
            __builtin_amdgcn_sched_barrier(0);

            v2f o0a, o1a, o0b, o1b;
            stepf(axr0, axi0, o0a, o1a);       // t = 2w
            stepf(axr1, axi1, o0b, o1b);       // t = 2w+1

            po0[0]  = o0a;  po1[0]  = o1a;     // cached stores (R10 winner)
            po0[TS] = o0b;  po1[TS] = o1b;
            po0 += 2 * TS;  po1 += 2 * TS;

            __builtin_amdgcn_s_barrier();
            __builtin_amdgcn_sched_barrier(0);
        }
    }
}

extern "C" void kernel_launch(void* const* d_in, const int* in_sizes, int n_in,
                              void* d_out, int out_size, void* d_ws, size_t ws_size,
                              hipStream_t stream) {
    const float* Xr = (const float*)d_in[0];
    const float* Xi = (const float*)d_in[1];
    const float* Om = (const float*)d_in[2];
    float* out = (float*)d_out;

    dim3 block(512);                // 8 waves: 4 producers + 4 consumers
    dim3 grid(BS * CHV2 / CPB);     // 512 blocks = 2 blocks/CU, 16 waves/CU
    hopf_scan_kernel<<<grid, block, 0, stream>>>(Xr, Xi, Om, out);
}